// Round 2
// baseline (83.710 us; speedup 1.0000x reference)
//
#include <hip/hip_runtime.h>

#define T_FRAMES 75
#define C_CH 3
#define HW4 (112 * 112 / 4)   // 3136 float4 per frame-slab
#define P_DEL 0.05f

// One block per (b, c, j) output frame-slab.
// Step 1: rebuild the per-batch delete mask in two 64-bit registers
//         (wave-uniform scalar work, no LDS, no scratch).
// Step 2: replay the reference scan tracking ONLY writes to slot j.
// Step 3: coalesced float4 copy of input frame src -> output slot j.
__global__ void jitter_fused_kernel(const float4* __restrict__ x,
                                    float4* __restrict__ out,
                                    const float* __restrict__ u) {
    int slab = blockIdx.x;                       // [0, B*C*T)
    int b   = slab / (C_CH * T_FRAMES);
    int rem = slab % (C_CH * T_FRAMES);
    int c   = rem / T_FRAMES;
    int j   = rem % T_FRAMES;

    // ---- build del bitmask (uniform across block; compiler emits SALU) ----
    const float* ub = u + b * T_FRAMES;
    unsigned long long m0 = 0ull, m1 = 0ull;
#pragma unroll
    for (int t = 0; t < 64; ++t)
        m0 |= (unsigned long long)(ub[t] < P_DEL) << t;
#pragma unroll
    for (int t = 64; t < T_FRAMES; ++t)
        m1 |= (unsigned long long)(ub[t] < P_DEL) << (t - 64);

    // ---- replay scan, record last write targeting slot j ----
    // Reference: out starts as copy of input -> default src = j.
    int s = j;
    int cnt = 0;
    for (int t = 0; t < T_FRAMES; ++t) {
        int d  = (t < 64) ? (int)((m0 >> t) & 1ull)
                          : (int)((m1 >> (t - 64)) & 1ull);
        int rt = T_FRAMES - 1 - t;               // prob_dup[t] = prob_del[T-1-t]
        int dp = (rt < 64) ? (int)((m0 >> rt) & 1ull)
                           : (int)((m1 >> (rt - 64)) & 1ull);
        // step 1: keep frame t if not deleted
        if (!d && cnt < T_FRAMES) {
            if (cnt == j) s = t;
            ++cnt;
        }
        // step 2: duplicate from INPUT index (cnt-1)
        if (dp && cnt > 0 && cnt < T_FRAMES) {
            if (cnt == j) s = cnt - 1;
            ++cnt;
        }
        // cnt is monotone: once past j, slot j can never be written again
        if (cnt > j) break;
    }

    // ---- coalesced slab copy: out[b,c,j,:,:] = x[b,c,s,:,:] ----
    const float4* srcp = x + ((size_t)(b * C_CH + c) * T_FRAMES + s) * HW4;
    float4*       dstp = out + (size_t)slab * HW4;
    for (int i = threadIdx.x; i < HW4; i += blockDim.x)
        dstp[i] = srcp[i];
}

extern "C" void kernel_launch(void* const* d_in, const int* in_sizes, int n_in,
                              void* d_out, int out_size, void* d_ws, size_t ws_size,
                              hipStream_t stream) {
    const float* x = (const float*)d_in[0];      // [B, C, T, H, W] fp32
    const float* u = (const float*)d_in[1];      // [B, T] fp32
    float* out = (float*)d_out;

    int B = in_sizes[1] / T_FRAMES;              // 16
    int slabs = B * C_CH * T_FRAMES;             // 3600

    jitter_fused_kernel<<<slabs, 256, 0, stream>>>(
        (const float4*)x, (float4*)out, u);
}

// Round 4
// 72.157 us; speedup vs baseline: 1.1601x; 1.1601x over previous
//
#include <hip/hip_runtime.h>

#define T_FRAMES 75
#define C_CH 3
#define HW4 (112 * 112 / 4)    // 3136 float4 per frame-slab
#define P_DEL 0.05f
#define COPY_THREADS 448       // 7 waves; 3136 / 448 == 7 exactly

typedef float f32x4 __attribute__((ext_vector_type(4)));

// One thread per (b, j): replay the reference scan tracking ONLY writes to
// slot j. No arrays -> no scratch. Early break: cnt is monotone, once
// cnt > j no later step can write slot j.
__global__ void jitter_map_kernel(const float* __restrict__ u,
                                  int* __restrict__ src_map) {
    int b = blockIdx.x;
    int j = threadIdx.x;
    if (j >= T_FRAMES) return;
    const float* ub = u + b * T_FRAMES;

    unsigned long long m0 = 0ull, m1 = 0ull;
#pragma unroll
    for (int t = 0; t < 64; ++t)
        m0 |= (unsigned long long)(ub[t] < P_DEL) << t;
#pragma unroll
    for (int t = 64; t < T_FRAMES; ++t)
        m1 |= (unsigned long long)(ub[t] < P_DEL) << (t - 64);

    int s = j;      // out starts as a copy of input
    int cnt = 0;
    for (int t = 0; t < T_FRAMES; ++t) {
        int d  = (t < 64) ? (int)((m0 >> t) & 1ull)
                          : (int)((m1 >> (t - 64)) & 1ull);
        int rt = T_FRAMES - 1 - t;              // prob_dup[t] = prob_del[T-1-t]
        int dp = (rt < 64) ? (int)((m0 >> rt) & 1ull)
                           : (int)((m1 >> (rt - 64)) & 1ull);
        if (!d && cnt < T_FRAMES) {             // keep frame t
            if (cnt == j) s = t;
            ++cnt;
        }
        if (dp && cnt > 0 && cnt < T_FRAMES) {  // dup from INPUT index cnt-1
            if (cnt == j) s = cnt - 1;
            ++cnt;
        }
        if (cnt > j) break;
    }
    src_map[b * T_FRAMES + j] = s;
}

// One block per (b, c, j) slab. 7 independent 16B loads in flight per
// thread, then 7 nontemporal stores (output is never re-read).
__global__ void __launch_bounds__(COPY_THREADS)
jitter_gather_kernel(const f32x4* __restrict__ x,
                     f32x4* __restrict__ out,
                     const int* __restrict__ src_map) {
    int slab = blockIdx.x;                        // [0, B*C*T)
    int b    = slab / (C_CH * T_FRAMES);
    int bc   = slab / T_FRAMES;                   // b*C + c
    int j    = slab % T_FRAMES;
    int s    = src_map[b * T_FRAMES + j];         // one wave-uniform load

    const f32x4* srcp = x   + ((size_t)bc * T_FRAMES + s) * HW4;
    f32x4*       dstp = out + (size_t)slab * HW4;

    int i = threadIdx.x;
    f32x4 r0 = srcp[i + 0 * COPY_THREADS];
    f32x4 r1 = srcp[i + 1 * COPY_THREADS];
    f32x4 r2 = srcp[i + 2 * COPY_THREADS];
    f32x4 r3 = srcp[i + 3 * COPY_THREADS];
    f32x4 r4 = srcp[i + 4 * COPY_THREADS];
    f32x4 r5 = srcp[i + 5 * COPY_THREADS];
    f32x4 r6 = srcp[i + 6 * COPY_THREADS];
    __builtin_nontemporal_store(r0, &dstp[i + 0 * COPY_THREADS]);
    __builtin_nontemporal_store(r1, &dstp[i + 1 * COPY_THREADS]);
    __builtin_nontemporal_store(r2, &dstp[i + 2 * COPY_THREADS]);
    __builtin_nontemporal_store(r3, &dstp[i + 3 * COPY_THREADS]);
    __builtin_nontemporal_store(r4, &dstp[i + 4 * COPY_THREADS]);
    __builtin_nontemporal_store(r5, &dstp[i + 5 * COPY_THREADS]);
    __builtin_nontemporal_store(r6, &dstp[i + 6 * COPY_THREADS]);
}

extern "C" void kernel_launch(void* const* d_in, const int* in_sizes, int n_in,
                              void* d_out, int out_size, void* d_ws, size_t ws_size,
                              hipStream_t stream) {
    const float* x = (const float*)d_in[0];       // [B, C, T, H, W] fp32
    const float* u = (const float*)d_in[1];       // [B, T] fp32
    float* out = (float*)d_out;
    int* src_map = (int*)d_ws;                    // B*T ints = 4.8 KB

    int B = in_sizes[1] / T_FRAMES;               // 16

    jitter_map_kernel<<<B, 128, 0, stream>>>(u, src_map);

    int slabs = B * C_CH * T_FRAMES;              // 3600
    jitter_gather_kernel<<<slabs, COPY_THREADS, 0, stream>>>(
        (const f32x4*)x, (f32x4*)out, src_map);
}

// Round 5
// 72.129 us; speedup vs baseline: 1.1606x; 1.0004x over previous
//
#include <hip/hip_runtime.h>

#define T_FRAMES 75
#define C_CH 3
#define HW4 (112 * 112 / 4)    // 3136 float4 per frame-slab
#define P_DEL 0.05f
#define COPY_THREADS 448       // 7 waves; 2 slabs: 2*3136 / 448 == 14 exactly

typedef float f32x4 __attribute__((ext_vector_type(4)));

// One thread per (b, j): replay the reference scan tracking ONLY writes to
// slot j. No arrays -> no scratch. Early break: cnt is monotone, once
// cnt > j no later step can write slot j.
__global__ void jitter_map_kernel(const float* __restrict__ u,
                                  int* __restrict__ src_map) {
    int b = blockIdx.x;
    int j = threadIdx.x;
    if (j >= T_FRAMES) return;
    const float* ub = u + b * T_FRAMES;

    unsigned long long m0 = 0ull, m1 = 0ull;
#pragma unroll
    for (int t = 0; t < 64; ++t)
        m0 |= (unsigned long long)(ub[t] < P_DEL) << t;
#pragma unroll
    for (int t = 64; t < T_FRAMES; ++t)
        m1 |= (unsigned long long)(ub[t] < P_DEL) << (t - 64);

    int s = j;      // out starts as a copy of input
    int cnt = 0;
    for (int t = 0; t < T_FRAMES; ++t) {
        int d  = (t < 64) ? (int)((m0 >> t) & 1ull)
                          : (int)((m1 >> (t - 64)) & 1ull);
        int rt = T_FRAMES - 1 - t;              // prob_dup[t] = prob_del[T-1-t]
        int dp = (rt < 64) ? (int)((m0 >> rt) & 1ull)
                           : (int)((m1 >> (rt - 64)) & 1ull);
        if (!d && cnt < T_FRAMES) {             // keep frame t
            if (cnt == j) s = t;
            ++cnt;
        }
        if (dp && cnt > 0 && cnt < T_FRAMES) {  // dup from INPUT index cnt-1
            if (cnt == j) s = cnt - 1;
            ++cnt;
        }
        if (cnt > j) break;
    }
    src_map[b * T_FRAMES + j] = s;
}

// Two slabs per block: 14 independent 16B loads in flight per thread,
// then 14 nontemporal stores (output is never re-read; don't evict the
// L3-resident input).
__global__ void __launch_bounds__(COPY_THREADS)
jitter_gather_kernel(const f32x4* __restrict__ x,
                     f32x4* __restrict__ out,
                     const int* __restrict__ src_map) {
    int slab0 = blockIdx.x * 2;                   // [0, B*C*T) in pairs
    int slab1 = slab0 + 1;

    int bc0 = slab0 / T_FRAMES, j0 = slab0 % T_FRAMES;
    int bc1 = slab1 / T_FRAMES, j1 = slab1 % T_FRAMES;
    int b0  = bc0 / C_CH,       b1  = bc1 / C_CH;
    int s0  = src_map[b0 * T_FRAMES + j0];
    int s1  = src_map[b1 * T_FRAMES + j1];

    const f32x4* sp0 = x   + ((size_t)bc0 * T_FRAMES + s0) * HW4;
    const f32x4* sp1 = x   + ((size_t)bc1 * T_FRAMES + s1) * HW4;
    f32x4*       dp0 = out + (size_t)slab0 * HW4;
    f32x4*       dp1 = out + (size_t)slab1 * HW4;

    int i = threadIdx.x;
    f32x4 a0 = sp0[i + 0 * COPY_THREADS];
    f32x4 a1 = sp0[i + 1 * COPY_THREADS];
    f32x4 a2 = sp0[i + 2 * COPY_THREADS];
    f32x4 a3 = sp0[i + 3 * COPY_THREADS];
    f32x4 a4 = sp0[i + 4 * COPY_THREADS];
    f32x4 a5 = sp0[i + 5 * COPY_THREADS];
    f32x4 a6 = sp0[i + 6 * COPY_THREADS];
    f32x4 c0 = sp1[i + 0 * COPY_THREADS];
    f32x4 c1 = sp1[i + 1 * COPY_THREADS];
    f32x4 c2 = sp1[i + 2 * COPY_THREADS];
    f32x4 c3 = sp1[i + 3 * COPY_THREADS];
    f32x4 c4 = sp1[i + 4 * COPY_THREADS];
    f32x4 c5 = sp1[i + 5 * COPY_THREADS];
    f32x4 c6 = sp1[i + 6 * COPY_THREADS];
    __builtin_nontemporal_store(a0, &dp0[i + 0 * COPY_THREADS]);
    __builtin_nontemporal_store(a1, &dp0[i + 1 * COPY_THREADS]);
    __builtin_nontemporal_store(a2, &dp0[i + 2 * COPY_THREADS]);
    __builtin_nontemporal_store(a3, &dp0[i + 3 * COPY_THREADS]);
    __builtin_nontemporal_store(a4, &dp0[i + 4 * COPY_THREADS]);
    __builtin_nontemporal_store(a5, &dp0[i + 5 * COPY_THREADS]);
    __builtin_nontemporal_store(a6, &dp0[i + 6 * COPY_THREADS]);
    __builtin_nontemporal_store(c0, &dp1[i + 0 * COPY_THREADS]);
    __builtin_nontemporal_store(c1, &dp1[i + 1 * COPY_THREADS]);
    __builtin_nontemporal_store(c2, &dp1[i + 2 * COPY_THREADS]);
    __builtin_nontemporal_store(c3, &dp1[i + 3 * COPY_THREADS]);
    __builtin_nontemporal_store(c4, &dp1[i + 4 * COPY_THREADS]);
    __builtin_nontemporal_store(c5, &dp1[i + 5 * COPY_THREADS]);
    __builtin_nontemporal_store(c6, &dp1[i + 6 * COPY_THREADS]);
}

extern "C" void kernel_launch(void* const* d_in, const int* in_sizes, int n_in,
                              void* d_out, int out_size, void* d_ws, size_t ws_size,
                              hipStream_t stream) {
    const float* x = (const float*)d_in[0];       // [B, C, T, H, W] fp32
    const float* u = (const float*)d_in[1];       // [B, T] fp32
    float* out = (float*)d_out;
    int* src_map = (int*)d_ws;                    // B*T ints = 4.8 KB

    int B = in_sizes[1] / T_FRAMES;               // 16

    jitter_map_kernel<<<B, 128, 0, stream>>>(u, src_map);

    int slab_pairs = B * C_CH * T_FRAMES / 2;     // 1800
    jitter_gather_kernel<<<slab_pairs, COPY_THREADS, 0, stream>>>(
        (const f32x4*)x, (f32x4*)out, src_map);
}

// Round 6
// 62.275 us; speedup vs baseline: 1.3442x; 1.1582x over previous
//
#include <hip/hip_runtime.h>

#define T_FRAMES 75
#define C_CH 3
#define HW4 (112 * 112 / 4)    // 3136 float4 per frame-slab
#define P_DEL 0.05f
#define COPY_THREADS 448       // 7 waves; 2 slabs: 2*3136 / 448 == 14 exactly

typedef float f32x4 __attribute__((ext_vector_type(4)));

// Replay the reference scan for ONE output slot j given the 75-bit delete
// mask (m0 = bits 0..63, m1 = bits 64..74). Returns the INPUT frame index
// that slot j ends up holding. cnt is monotone -> early break once cnt > j.
__device__ __forceinline__ int jitter_replay(unsigned long long m0,
                                             unsigned long long m1, int j) {
    int s = j;      // out starts as a copy of input
    int cnt = 0;
    for (int t = 0; t < T_FRAMES; ++t) {
        int d  = (int)(((t < 64 ? m0 : m1) >> (t & 63)) & 1ull);
        int rt = T_FRAMES - 1 - t;              // prob_dup[t] = prob_del[T-1-t]
        int dp = (int)(((rt < 64 ? m0 : m1) >> (rt & 63)) & 1ull);
        if (!d && cnt < T_FRAMES) {             // keep frame t
            if (cnt == j) s = t;
            ++cnt;
        }
        if (dp && cnt > 0 && cnt < T_FRAMES) {  // dup from INPUT index cnt-1
            if (cnt == j) s = cnt - 1;
            ++cnt;
        }
        if (cnt > j) break;                     // uniform across lanes
    }
    return s;
}

// Build the 75-bit delete mask for batch b via two wave ballots.
__device__ __forceinline__ void build_mask(const float* __restrict__ u, int b,
                                           int lane, unsigned long long& m0,
                                           unsigned long long& m1) {
    const float* ub = u + b * T_FRAMES;
    float v0 = ub[lane];                                  // lanes 0..63
    m0 = __ballot(v0 < P_DEL);
    float v1 = (lane < T_FRAMES - 64) ? ub[64 + lane] : 1.0f;
    m1 = __ballot(v1 < P_DEL);
}

// One block per pair of (b, c, j) output frame-slabs. Wave 0 computes the
// two source indices (ballot masks + early-break replay), broadcasts via
// LDS; all 7 waves then do a 14-deep float4 copy with nontemporal stores.
__global__ void __launch_bounds__(COPY_THREADS)
jitter_fused_kernel(const f32x4* __restrict__ x,
                    f32x4* __restrict__ out,
                    const float* __restrict__ u) {
    __shared__ int s_lds[2];

    int slab0 = blockIdx.x * 2;                   // [0, B*C*T) in pairs
    int slab1 = slab0 + 1;
    int bc0 = slab0 / T_FRAMES, j0 = slab0 % T_FRAMES;
    int bc1 = slab1 / T_FRAMES, j1 = slab1 % T_FRAMES;
    int b0  = bc0 / C_CH,       b1  = bc1 / C_CH;

    if (threadIdx.x < 64) {                       // wave 0 only
        int lane = threadIdx.x;
        unsigned long long m0, m1;
        build_mask(u, b0, lane, m0, m1);
        int s0 = jitter_replay(m0, m1, j0);
        int s1;
        if (b1 == b0) {
            s1 = jitter_replay(m0, m1, j1);
        } else {
            unsigned long long n0, n1;
            build_mask(u, b1, lane, n0, n1);
            s1 = jitter_replay(n0, n1, j1);
        }
        if (lane == 0) { s_lds[0] = s0; s_lds[1] = s1; }
    }
    __syncthreads();
    int s0 = s_lds[0];
    int s1 = s_lds[1];

    const f32x4* sp0 = x   + ((size_t)bc0 * T_FRAMES + s0) * HW4;
    const f32x4* sp1 = x   + ((size_t)bc1 * T_FRAMES + s1) * HW4;
    f32x4*       dp0 = out + (size_t)slab0 * HW4;
    f32x4*       dp1 = out + (size_t)slab1 * HW4;

    int i = threadIdx.x;
    f32x4 a0 = sp0[i + 0 * COPY_THREADS];
    f32x4 a1 = sp0[i + 1 * COPY_THREADS];
    f32x4 a2 = sp0[i + 2 * COPY_THREADS];
    f32x4 a3 = sp0[i + 3 * COPY_THREADS];
    f32x4 a4 = sp0[i + 4 * COPY_THREADS];
    f32x4 a5 = sp0[i + 5 * COPY_THREADS];
    f32x4 a6 = sp0[i + 6 * COPY_THREADS];
    f32x4 c0 = sp1[i + 0 * COPY_THREADS];
    f32x4 c1 = sp1[i + 1 * COPY_THREADS];
    f32x4 c2 = sp1[i + 2 * COPY_THREADS];
    f32x4 c3 = sp1[i + 3 * COPY_THREADS];
    f32x4 c4 = sp1[i + 4 * COPY_THREADS];
    f32x4 c5 = sp1[i + 5 * COPY_THREADS];
    f32x4 c6 = sp1[i + 6 * COPY_THREADS];
    __builtin_nontemporal_store(a0, &dp0[i + 0 * COPY_THREADS]);
    __builtin_nontemporal_store(a1, &dp0[i + 1 * COPY_THREADS]);
    __builtin_nontemporal_store(a2, &dp0[i + 2 * COPY_THREADS]);
    __builtin_nontemporal_store(a3, &dp0[i + 3 * COPY_THREADS]);
    __builtin_nontemporal_store(a4, &dp0[i + 4 * COPY_THREADS]);
    __builtin_nontemporal_store(a5, &dp0[i + 5 * COPY_THREADS]);
    __builtin_nontemporal_store(a6, &dp0[i + 6 * COPY_THREADS]);
    __builtin_nontemporal_store(c0, &dp1[i + 0 * COPY_THREADS]);
    __builtin_nontemporal_store(c1, &dp1[i + 1 * COPY_THREADS]);
    __builtin_nontemporal_store(c2, &dp1[i + 2 * COPY_THREADS]);
    __builtin_nontemporal_store(c3, &dp1[i + 3 * COPY_THREADS]);
    __builtin_nontemporal_store(c4, &dp1[i + 4 * COPY_THREADS]);
    __builtin_nontemporal_store(c5, &dp1[i + 5 * COPY_THREADS]);
    __builtin_nontemporal_store(c6, &dp1[i + 6 * COPY_THREADS]);
}

extern "C" void kernel_launch(void* const* d_in, const int* in_sizes, int n_in,
                              void* d_out, int out_size, void* d_ws, size_t ws_size,
                              hipStream_t stream) {
    const float* x = (const float*)d_in[0];       // [B, C, T, H, W] fp32
    const float* u = (const float*)d_in[1];       // [B, T] fp32
    float* out = (float*)d_out;

    int B = in_sizes[1] / T_FRAMES;               // 16
    int slab_pairs = B * C_CH * T_FRAMES / 2;     // 1800

    jitter_fused_kernel<<<slab_pairs, COPY_THREADS, 0, stream>>>(
        (const f32x4*)x, (f32x4*)out, u);
}